// Round 13
// baseline (989.106 us; speedup 1.0000x reference)
//
#include <hip/hip_runtime.h>
#include <stdint.h>

typedef __attribute__((ext_vector_type(8))) _Float16 half8;
typedef __attribute__((ext_vector_type(2))) _Float16 half2v;
typedef __attribute__((ext_vector_type(4))) float floatx4;
typedef __attribute__((ext_vector_type(4))) uint32_t uint4v;

#define KDIM 4096
#define NDIM 11008
#define NKT 64

#define GLOAD_LDS16(gsrc, ldst)                                                        \
  __builtin_amdgcn_global_load_lds(                                                    \
      (const __attribute__((address_space(1))) void*)(gsrc),                           \
      (__attribute__((address_space(3))) void*)(ldst), 16, 0, 0)

static __device__ __forceinline__ uint32_t pkrtz(float a, float b) {
  auto h = __builtin_amdgcn_cvt_pkrtz(a, b);  // exact: values fp16-representable
  return __builtin_bit_cast(uint32_t, h);
}

// int32 of 8 nibbles -> half8 of (q-8)/7.5*s in k-order; exact (q-8) via 0x6400 trick.
static __device__ __forceinline__ half8 dq8(uint32_t q, half2v ssv) {
  half2v off; off[0] = (_Float16)(-1032.0f); off[1] = (_Float16)(-1032.0f);
  const uint32_t a0 = (q & 0x000F000Fu) | 0x64006400u;
  const uint32_t a1 = ((q >> 4) & 0x000F000Fu) | 0x64006400u;
  const uint32_t a2 = ((q >> 8) & 0x000F000Fu) | 0x64006400u;
  const uint32_t a3 = ((q >> 12) & 0x000F000Fu) | 0x64006400u;
  const uint32_t p0 = __builtin_amdgcn_perm(a1, a0, 0x05040100u);
  const uint32_t p1 = __builtin_amdgcn_perm(a3, a2, 0x05040100u);
  const uint32_t p2 = __builtin_amdgcn_perm(a1, a0, 0x07060302u);
  const uint32_t p3 = __builtin_amdgcn_perm(a3, a2, 0x07060302u);
  uint4v u;
  u[0] = __builtin_bit_cast(uint32_t, (__builtin_bit_cast(half2v, p0) + off) * ssv);
  u[1] = __builtin_bit_cast(uint32_t, (__builtin_bit_cast(half2v, p1) + off) * ssv);
  u[2] = __builtin_bit_cast(uint32_t, (__builtin_bit_cast(half2v, p2) + off) * ssv);
  u[3] = __builtin_bit_cast(uint32_t, (__builtin_bit_cast(half2v, p3) + off) * ssv);
  return __builtin_bit_cast(half8, u);
}

// ---------------- prepass 1: fp32 -> fp16 copy of X ----------------
__global__ __launch_bounds__(256)
void l4b_prep(const float* __restrict__ in, _Float16* __restrict__ out, int n8) {
  int i = blockIdx.x * 256 + threadIdx.x;
  if (i < n8) {
    floatx4 v0 = ((const floatx4*)in)[2 * i];
    floatx4 v1 = ((const floatx4*)in)[2 * i + 1];
    uint4v u;
    u[0] = pkrtz(v0[0], v0[1]); u[1] = pkrtz(v0[2], v0[3]);
    u[2] = pkrtz(v1[0], v1[1]); u[3] = pkrtz(v1[2], v1[3]);
    ((uint4v*)out)[i] = u;
  }
}

// ---------------- prepass 2: dequant + transpose PW -> BH[N][K] fp16 ----------------
__global__ __launch_bounds__(256)
void l4b_prepB(const int* __restrict__ PW, const float* __restrict__ SC,
               _Float16* __restrict__ BH) {
  __shared__ alignas(16) _Float16 lt[64 * 64];
  const int t  = threadIdx.x;
  const int nb = NDIM / 64;           // 172
  const int kb = blockIdx.x / nb;     // 0..63
  const int n0 = (blockIdx.x - kb * nb) * 64;
  const int kp0 = kb * 8;
#pragma unroll
  for (int h = 0; h < 2; ++h) {
    const int idx  = t + h * 256;
    const int kp_l = idx >> 6;
    const int n_l  = idx & 63;
    const int kp   = kp0 + kp_l;
    const uint32_t q = (uint32_t)PW[kp * NDIM + n0 + n_l];
    const float    s = SC[(kp >> 4) * NDIM + n0 + n_l];
    const _Float16 ss = (_Float16)(s * (1.0f / 7.5f));
    half2v sv; sv[0] = ss; sv[1] = ss;
    half8 v = dq8(q, sv);
    *(half8*)&lt[n_l * 64 + ((kp_l ^ (n_l & 7)) * 8)] = v;
  }
  __syncthreads();
  const int n_l = t >> 2;
  const int c   = t & 3;
  uint4v o0 = *(uint4v*)&lt[n_l * 64 + (((c * 2) ^ (n_l & 7)) * 8)];
  uint4v o1 = *(uint4v*)&lt[n_l * 64 + (((c * 2 + 1) ^ (n_l & 7)) * 8)];
  _Float16* op = BH + (int64_t)(n0 + n_l) * KDIM + kp0 * 8 + c * 16;
  *(uint4v*)op       = o0;
  *(uint4v*)(op + 8) = o1;
}

// ---- main: 256x128 tile, TRIPLE-buffered (144KB LDS), counted vmcnt(6) never->0,
//      all-DMA staging, 1 barrier/kt, wave-slip interior ----
__global__ __launch_bounds__(512, 1)
void l4b_g6(const _Float16* __restrict__ XH,
            const _Float16* __restrict__ BH,
            float* __restrict__ OUT)
{
  // Rows of 64 halves = 128B = 8 x 16B slots; phys slot p holds logical p ^ (row&7).
  // Proven conflict-free for ds_read_b128 fragments + DMA with pre-swizzled source.
  __shared__ alignas(16) _Float16 la[3][256 * 64];  // 96 KB
  __shared__ alignas(16) _Float16 lb[3][128 * 64];  // 48 KB  -> 144 KB total

  const int tid  = threadIdx.x;
  const int lane = tid & 63;
  const int wave = tid >> 6;

  // XCD-aware bijective swizzle (grid = 2752 = 8*344)
  const int cpx = (int)gridDim.x >> 3;
  const int wg  = ((int)blockIdx.x & 7) * cpx + ((int)blockIdx.x >> 3);
  const int by  = wg / 86;
  const int bx  = wg - by * 86;
  const int64_t brow = (int64_t)by * 256;
  const int     bcol = bx * 128;

  // 4M x 2N wave grid, wave tile 64x64
  const int wr = (wave >> 1) * 64;
  const int wc = (wave & 1) * 64;
  const int fr = lane & 15;
  const int fq = lane >> 4;

  floatx4 acc[4][4];
#pragma unroll
  for (int i = 0; i < 4; ++i)
#pragma unroll
    for (int j = 0; j < 4; ++j) acc[i][j] = (floatx4)(0.0f);

  // DMA: A per wave 4 insts (rows wave*32 .. +31), B per wave 2 insts (rows wave*16 .. +15)
  const int arow8 = lane >> 3;
  const int aslot = (lane & 7) ^ arow8;  // pre-swizzled source slot
  const _Float16* const asrc0 =
      XH + (brow + wave * 32 + arow8) * (int64_t)KDIM + aslot * 8;
  const _Float16* const bsrc0 =
      BH + (bcol + wave * 16 + arow8) * (int64_t)KDIM + aslot * 8;

#define DMA_T(t, s)                                                        \
  do {                                                                     \
    _Pragma("unroll") for (int g8 = 0; g8 < 4; ++g8)                       \
        GLOAD_LDS16(asrc0 + (int64_t)g8 * 8 * KDIM + (t) * 64,             \
                    &la[s][(wave * 32 + g8 * 8) * 64]);                    \
    _Pragma("unroll") for (int g8 = 0; g8 < 2; ++g8)                       \
        GLOAD_LDS16(bsrc0 + (int64_t)g8 * 8 * KDIM + (t) * 64,             \
                    &lb[s][(wave * 16 + g8 * 8) * 64]);                    \
  } while (0)

#define READ_B4(dstf, s, ksl)                                              \
  _Pragma("unroll") for (int fn_ = 0; fn_ < 4; ++fn_) {                    \
    const int n_ = wc + fn_ * 16 + fr;                                     \
    dstf[fn_] = *(const half8*)&lb[s][n_ * 64 + (((ksl) ^ (n_ & 7)) * 8)]; \
  }

#define READ_A4(dstf, s, ksl)                                              \
  _Pragma("unroll") for (int fm_ = 0; fm_ < 4; ++fm_) {                    \
    const int m_ = wr + fm_ * 16 + fr;                                     \
    dstf[fm_] = *(const half8*)&la[s][m_ * 64 + (((ksl) ^ (m_ & 7)) * 8)]; \
  }

#define MFMA16(afv, bfv)                                                   \
  __builtin_amdgcn_s_setprio(1);                                           \
  _Pragma("unroll") for (int fm_ = 0; fm_ < 4; ++fm_)                      \
  _Pragma("unroll") for (int fn_ = 0; fn_ < 4; ++fn_)                      \
      acc[fm_][fn_] = __builtin_amdgcn_mfma_f32_16x16x32_f16(              \
          afv[fm_], bfv[fn_], acc[fm_][fn_], 0, 0, 0);                     \
  __builtin_amdgcn_s_setprio(0);

  // One K-step on ring slot CUR; issues tile KT+2 into slot NXT (the slot that
  // held tile KT-1, freed last kt). End wait: vmcnt(6) retires tile KT+1's loads
  // (issued one kt ago) while KT+2's 6 stay in flight. Never 0 until the tail.
#define KT_BODY(KT, CUR, NXT)                                              \
  do {                                                                     \
    if ((KT) + 2 < NKT) DMA_T((KT) + 2, NXT);                              \
    __builtin_amdgcn_sched_barrier(0);                                     \
    half8 b0[4], b1[4], aA[4], aB[4];                                      \
    READ_B4(b0, CUR, fq);                                                  \
    READ_A4(aA, CUR, fq);                                                  \
    READ_B4(b1, CUR, 4 + fq);                                              \
    READ_A4(aB, CUR, 4 + fq);                                              \
    MFMA16(aA, b0);                                                        \
    MFMA16(aB, b1);                                                        \
    __builtin_amdgcn_sched_barrier(0);                                     \
    if ((KT) < 62) { asm volatile("s_waitcnt vmcnt(6)" ::: "memory"); }    \
    else           { asm volatile("s_waitcnt vmcnt(0)" ::: "memory"); }    \
    __builtin_amdgcn_s_barrier();                                          \
    __builtin_amdgcn_sched_barrier(0);                                     \
  } while (0)

  // ---- prologue: issue tiles 0,1; wait tile 0 (vmcnt(6) leaves tile 1 flying) ----
  DMA_T(0, 0);
  DMA_T(1, 1);
  asm volatile("s_waitcnt vmcnt(6)" ::: "memory");
  __builtin_amdgcn_s_barrier();
  __builtin_amdgcn_sched_barrier(0);

  // kt = 0..62 in unroll-3 groups (static ring slots), kt=63 peeled (no barrier)
  for (int base = 0; base < 63; base += 3) {
    KT_BODY(base + 0, 0, 2);
    KT_BODY(base + 1, 1, 0);
    KT_BODY(base + 2, 2, 1);
  }
  {  // kt = 63, slot 0; tile already complete (vmcnt(0) at kt=62)
    half8 b0[4], b1[4], aA[4], aB[4];
    READ_B4(b0, 0, fq);
    READ_A4(aA, 0, fq);
    READ_B4(b1, 0, 4 + fq);
    READ_A4(aB, 0, 4 + fq);
    MFMA16(aA, b0);
    MFMA16(aB, b1);
  }

  // ---- epilogue: C/D map col=lane&15, row=(lane>>4)*4+reg; fp32 out ----
#pragma unroll
  for (int fm = 0; fm < 4; ++fm)
#pragma unroll
    for (int fn = 0; fn < 4; ++fn)
#pragma unroll
      for (int r = 0; r < 4; ++r) {
        const int64_t row = brow + wr + fm * 16 + fq * 4 + r;
        const int     col = bcol + wc + fn * 16 + fr;
        OUT[row * NDIM + col] = acc[fm][fn][r];
      }
}

// ---------------- fallback (fp32-input, no workspace; proven r3 structure) ----------------
__global__ __launch_bounds__(512, 2)
void l4b_fb(const float* __restrict__ X, const int* __restrict__ PW,
            const float* __restrict__ SC, float* __restrict__ OUT)
{
  __shared__ alignas(16) _Float16 fla[2][256 * 64];
  __shared__ alignas(16) _Float16 flb[2][256 * 64];

  const int tid  = threadIdx.x;
  const int lane = tid & 63;
  const int wave = tid >> 6;

  const int cpx = (int)gridDim.x >> 3;
  const int wg  = ((int)blockIdx.x & 7) * cpx + ((int)blockIdx.x >> 3);
  const int by  = wg / 43;
  const int bx  = wg - by * 43;
  const int64_t brow = (int64_t)by * 256;
  const int     bcol = bx * 256;

  const int wr = (wave >> 2) * 128;
  const int wc = (wave & 3) * 64;
  const int fr = lane & 15;
  const int fq = lane >> 4;

  floatx4 acc[8][4];
#pragma unroll
  for (int i = 0; i < 8; ++i)
#pragma unroll
    for (int j = 0; j < 4; ++j) acc[i][j] = (floatx4)(0.0f);

  const int ar = tid >> 1;
  const int ah = tid & 1;
  const float* const aptr = X + (brow + ar) * (int64_t)KDIM + ah * 32;
  const int bc  = tid & 255;
  const int bkq = tid >> 8;
  const int*   const pwcol = PW + bcol + bc;
  const float* const sccol = SC + bcol + bc;

  floatx4 ra[8];
  int     rwf[4];
  float   rsc;

#define F_LOAD_A(t)                                                        \
  do {                                                                     \
    const float* ap = aptr + (t) * 64;                                     \
    _Pragma("unroll") for (int i_ = 0; i_ < 8; ++i_)                       \
        ra[i_] = *(const floatx4*)(ap + i_ * 4);                           \
  } while (0)

#define F_LOAD_B(t)                                                        \
  do {                                                                     \
    const int* pp = pwcol + ((t) * 8 + bkq) * NDIM;                        \
    _Pragma("unroll") for (int j_ = 0; j_ < 4; ++j_)                       \
        rwf[j_] = pp[j_ * 2 * NDIM];                                       \
    rsc = sccol[(int64_t)((t) >> 1) * NDIM];                               \
  } while (0)

#define F_WRITE_A(dst)                                                     \
  do {                                                                     \
    _Pragma("unroll") for (int i2 = 0; i2 < 4; ++i2) {                     \
      uint4v u;                                                            \
      u[0] = pkrtz(ra[2 * i2][0], ra[2 * i2][1]);                          \
      u[1] = pkrtz(ra[2 * i2][2], ra[2 * i2][3]);                          \
      u[2] = pkrtz(ra[2 * i2 + 1][0], ra[2 * i2 + 1][1]);                  \
      u[3] = pkrtz(ra[2 * i2 + 1][2], ra[2 * i2 + 1][3]);                  \
      const int s_ = ah * 4 + i2;                                          \
      *(half8*)&(dst)[ar * 64 + ((s_ ^ (ar & 7)) * 8)] =                   \
          __builtin_bit_cast(half8, u);                                    \
    }                                                                      \
  } while (0)

#define F_WRITE_B(dst)                                                     \
  do {                                                                     \
    const _Float16 ssf = (_Float16)(rsc * (1.0f / 7.5f));                  \
    half2v sv; sv[0] = ssf; sv[1] = ssf;                                   \
    _Pragma("unroll") for (int j_ = 0; j_ < 4; ++j_) {                     \
      half8 v = dq8((uint32_t)rwf[j_], sv);                                \
      const int kp = bkq + 2 * j_;                                         \
      *(half8*)&(dst)[bc * 64 + ((kp ^ (bc & 7)) * 8)] = v;                \
    }                                                                      \
  } while (0)

#define F_MFMA16(fm0)                                                      \
  __builtin_amdgcn_s_barrier();                                            \
  asm volatile("s_waitcnt lgkmcnt(0)" ::: "memory");                       \
  __builtin_amdgcn_sched_barrier(0);                                       \
  __builtin_amdgcn_s_setprio(1);                                           \
  _Pragma("unroll") for (int fm_ = 0; fm_ < 4; ++fm_)                      \
  _Pragma("unroll") for (int fn_ = 0; fn_ < 4; ++fn_)                      \
      acc[(fm0) + fm_][fn_] = __builtin_amdgcn_mfma_f32_16x16x32_f16(      \
          af[fm_], bfr[fn_], acc[(fm0) + fm_][fn_], 0, 0, 0);              \
  __builtin_amdgcn_s_setprio(0);                                           \
  __builtin_amdgcn_sched_barrier(0);                                       \
  __builtin_amdgcn_s_barrier();                                            \
  __builtin_amdgcn_sched_barrier(0);

  F_LOAD_A(0); F_LOAD_B(0);
  F_WRITE_A(fla[0]); F_WRITE_B(flb[0]);
  F_LOAD_A(1); F_LOAD_B(1);
  asm volatile("s_waitcnt lgkmcnt(0)" ::: "memory");
  __builtin_amdgcn_s_barrier();
  __builtin_amdgcn_sched_barrier(0);

  for (int kt = 0; kt < NKT; ++kt) {
    const int buf = kt & 1;
    const _Float16* lap = fla[buf];
    const _Float16* lbp = flb[buf];
    _Float16* const lan = fla[buf ^ 1];
    _Float16* const lbn = flb[buf ^ 1];
    const bool haveW = (kt + 1 < NKT);
    const bool haveL = (kt + 2 < NKT);

    half8 bfr[4], af[4];

#pragma unroll
    for (int fn_ = 0; fn_ < 4; ++fn_) {
      const int n_ = wc + fn_ * 16 + fr;
      bfr[fn_] = *(const half8*)&lbp[n_ * 64 + ((fq ^ (n_ & 7)) * 8)];
    }
#pragma unroll
    for (int fm_ = 0; fm_ < 4; ++fm_) {
      const int m_ = wr + fm_ * 16 + fr;
      af[fm_] = *(const half8*)&lap[m_ * 64 + ((fq ^ (m_ & 7)) * 8)];
    }
    if (haveW) F_WRITE_A(lan);
    F_MFMA16(0);

#pragma unroll
    for (int fm_ = 0; fm_ < 4; ++fm_) {
      const int m_ = wr + (4 + fm_) * 16 + fr;
      af[fm_] = *(const half8*)&lap[m_ * 64 + ((fq ^ (m_ & 7)) * 8)];
    }
    if (haveL) F_LOAD_A(kt + 2);
    F_MFMA16(4);

#pragma unroll
    for (int fn_ = 0; fn_ < 4; ++fn_) {
      const int n_ = wc + fn_ * 16 + fr;
      bfr[fn_] = *(const half8*)&lbp[n_ * 64 + (((4 + fq) ^ (n_ & 7)) * 8)];
    }
#pragma unroll
    for (int fm_ = 0; fm_ < 4; ++fm_) {
      const int m_ = wr + fm_ * 16 + fr;
      af[fm_] = *(const half8*)&lap[m_ * 64 + (((4 + fq) ^ (m_ & 7)) * 8)];
    }
    if (haveW) F_WRITE_B(lbn);
    F_MFMA16(0);

#pragma unroll
    for (int fm_ = 0; fm_ < 4; ++fm_) {
      const int m_ = wr + (4 + fm_) * 16 + fr;
      af[fm_] = *(const half8*)&lap[m_ * 64 + (((4 + fq) ^ (m_ & 7)) * 8)];
    }
    if (haveL) F_LOAD_B(kt + 2);
    F_MFMA16(4);
  }

#pragma unroll
  for (int fm = 0; fm < 8; ++fm)
#pragma unroll
    for (int fn = 0; fn < 4; ++fn)
#pragma unroll
      for (int r = 0; r < 4; ++r) {
        const int64_t row = brow + wr + fm * 16 + fq * 4 + r;
        const int     col = bcol + wc + fn * 16 + fr;
        OUT[row * NDIM + col] = acc[fm][fn][r];
      }
}

extern "C" void kernel_launch(void* const* d_in, const int* in_sizes, int n_in,
                              void* d_out, int out_size, void* d_ws, size_t ws_size,
                              hipStream_t stream) {
  const float* X   = (const float*)d_in[0];
  const int*   PW  = (const int*)d_in[1];
  const float* SC  = (const float*)d_in[2];
  float*       OUT = (float*)d_out;

  const int    M     = in_sizes[0] / KDIM;                 // 8192
  const size_t needH = (size_t)in_sizes[0] * 2;            // 67.1 MB fp16 X
  const size_t needB = (size_t)KDIM * NDIM * 2;            // 90.2 MB fp16 B

  if (ws_size >= needH + needB && (M % 256) == 0) {
    _Float16* XH = (_Float16*)d_ws;
    _Float16* BH = (_Float16*)((char*)d_ws + needH);
    const int n8 = in_sizes[0] / 8;
    l4b_prep<<<(n8 + 255) / 256, 256, 0, stream>>>(X, XH, n8);
    l4b_prepB<<<(KDIM / 64) * (NDIM / 64), 256, 0, stream>>>(PW, SC, BH);
    const int grid = (M / 256) * (NDIM / 128);             // 32*86 = 2752
    l4b_g6<<<grid, 512, 0, stream>>>(XH, BH, OUT);
  } else {
    const int grid = (M / 256) * (NDIM / 256);             // 1376
    l4b_fb<<<grid, 512, 0, stream>>>(X, PW, SC, OUT);
  }
}

// Round 14
// 964.284 us; speedup vs baseline: 1.0257x; 1.0257x over previous
//
#include <hip/hip_runtime.h>
#include <stdint.h>

typedef __attribute__((ext_vector_type(8))) _Float16 half8;
typedef __attribute__((ext_vector_type(2))) _Float16 half2v;
typedef __attribute__((ext_vector_type(4))) float floatx4;
typedef __attribute__((ext_vector_type(4))) uint32_t uint4v;

#define KDIM 4096
#define NDIM 11008
#define NKT 64

#define GLOAD_LDS16(gsrc, ldst)                                                        \
  __builtin_amdgcn_global_load_lds(                                                    \
      (const __attribute__((address_space(1))) void*)(gsrc),                           \
      (__attribute__((address_space(3))) void*)(ldst), 16, 0, 0)

static __device__ __forceinline__ uint32_t pkrtz(float a, float b) {
  auto h = __builtin_amdgcn_cvt_pkrtz(a, b);  // exact: values fp16-representable
  return __builtin_bit_cast(uint32_t, h);
}

// int32 of 8 nibbles -> half8 of (q-8)/7.5*s in k-order; exact (q-8) via 0x6400 trick.
static __device__ __forceinline__ half8 dq8(uint32_t q, half2v ssv) {
  half2v off; off[0] = (_Float16)(-1032.0f); off[1] = (_Float16)(-1032.0f);
  const uint32_t a0 = (q & 0x000F000Fu) | 0x64006400u;
  const uint32_t a1 = ((q >> 4) & 0x000F000Fu) | 0x64006400u;
  const uint32_t a2 = ((q >> 8) & 0x000F000Fu) | 0x64006400u;
  const uint32_t a3 = ((q >> 12) & 0x000F000Fu) | 0x64006400u;
  const uint32_t p0 = __builtin_amdgcn_perm(a1, a0, 0x05040100u);
  const uint32_t p1 = __builtin_amdgcn_perm(a3, a2, 0x05040100u);
  const uint32_t p2 = __builtin_amdgcn_perm(a1, a0, 0x07060302u);
  const uint32_t p3 = __builtin_amdgcn_perm(a3, a2, 0x07060302u);
  uint4v u;
  u[0] = __builtin_bit_cast(uint32_t, (__builtin_bit_cast(half2v, p0) + off) * ssv);
  u[1] = __builtin_bit_cast(uint32_t, (__builtin_bit_cast(half2v, p1) + off) * ssv);
  u[2] = __builtin_bit_cast(uint32_t, (__builtin_bit_cast(half2v, p2) + off) * ssv);
  u[3] = __builtin_bit_cast(uint32_t, (__builtin_bit_cast(half2v, p3) + off) * ssv);
  return __builtin_bit_cast(half8, u);
}

// ---------------- prepass 1: fp32 -> fp16 copy of X ----------------
__global__ __launch_bounds__(256)
void l4b_prep(const float* __restrict__ in, _Float16* __restrict__ out, int n8) {
  int i = blockIdx.x * 256 + threadIdx.x;
  if (i < n8) {
    floatx4 v0 = ((const floatx4*)in)[2 * i];
    floatx4 v1 = ((const floatx4*)in)[2 * i + 1];
    uint4v u;
    u[0] = pkrtz(v0[0], v0[1]); u[1] = pkrtz(v0[2], v0[3]);
    u[2] = pkrtz(v1[0], v1[1]); u[3] = pkrtz(v1[2], v1[3]);
    ((uint4v*)out)[i] = u;
  }
}

// ---------------- prepass 2: dequant + transpose PW -> BH[N][K] fp16 ----------------
__global__ __launch_bounds__(256)
void l4b_prepB(const int* __restrict__ PW, const float* __restrict__ SC,
               _Float16* __restrict__ BH) {
  __shared__ alignas(16) _Float16 lt[64 * 64];
  const int t  = threadIdx.x;
  const int nb = NDIM / 64;           // 172
  const int kb = blockIdx.x / nb;     // 0..63
  const int n0 = (blockIdx.x - kb * nb) * 64;
  const int kp0 = kb * 8;
#pragma unroll
  for (int h = 0; h < 2; ++h) {
    const int idx  = t + h * 256;
    const int kp_l = idx >> 6;
    const int n_l  = idx & 63;
    const int kp   = kp0 + kp_l;
    const uint32_t q = (uint32_t)PW[kp * NDIM + n0 + n_l];
    const float    s = SC[(kp >> 4) * NDIM + n0 + n_l];
    const _Float16 ss = (_Float16)(s * (1.0f / 7.5f));
    half2v sv; sv[0] = ss; sv[1] = ss;
    half8 v = dq8(q, sv);
    *(half8*)&lt[n_l * 64 + ((kp_l ^ (n_l & 7)) * 8)] = v;
  }
  __syncthreads();
  const int n_l = t >> 2;
  const int c   = t & 3;
  uint4v o0 = *(uint4v*)&lt[n_l * 64 + (((c * 2) ^ (n_l & 7)) * 8)];
  uint4v o1 = *(uint4v*)&lt[n_l * 64 + (((c * 2 + 1) ^ (n_l & 7)) * 8)];
  _Float16* op = BH + (int64_t)(n0 + n_l) * KDIM + kp0 * 8 + c * 16;
  *(uint4v*)op       = o0;
  *(uint4v*)(op + 8) = o1;
}

// ---- main: 256x256 fp16 GEMM, m201-style 4-phase/tile fine interleave,
//      k-half (16KB) staging granularity, counted vmcnt(6), never 0 in steady state ----
__global__ __launch_bounds__(512, 2)
void l4b_g7(const _Float16* __restrict__ XH,
            const _Float16* __restrict__ BH,
            float* __restrict__ OUT)
{
  // Per operand: [2 dbuf][2 khalf][128 lines]; line = 128B = row-pair (2 rows x 32 halves).
  // Phys 16B slot p in line j holds logical (rowparity rho, kslot sig): p = (rho*4+sig) ^ (j&7).
  // Fragment reads: 8 lanes per line cover all 8 slots -> conflict-free; p lane-constant.
  __shared__ alignas(16) _Float16 lA[2][2][128 * 64];  // 64 KB
  __shared__ alignas(16) _Float16 lB[2][2][128 * 64];  // 64 KB

  const int tid  = threadIdx.x;
  const int lane = tid & 63;
  const int wave = tid >> 6;

  // XCD-aware bijective swizzle (grid = 1376 = 8*172)
  const int cpx = (int)gridDim.x >> 3;
  const int wg  = ((int)blockIdx.x & 7) * cpx + ((int)blockIdx.x >> 3);
  const int by  = wg / 43;
  const int bx  = wg - by * 43;
  const int64_t brow = (int64_t)by * 256;
  const int     bcol = bx * 256;

  // 2M x 4N wave grid, wave tile 128x64
  const int wr = (wave >> 2) * 128;
  const int wc = (wave & 3) * 64;
  const int fr = lane & 15;
  const int fq = lane >> 4;

  floatx4 acc[8][4];
#pragma unroll
  for (int i = 0; i < 8; ++i)
#pragma unroll
    for (int j = 0; j < 4; ++j) acc[i][j] = (floatx4)(0.0f);

  // DMA source (per lane): line-local slot s_l = (l&7)^((l>>3)&7) -> (rho, sig)
  const int s_l  = (lane & 7) ^ ((lane >> 3) & 7);
  const int rho  = s_l >> 2;
  const int sig  = s_l & 3;
  const _Float16* const asrcA =
      XH + (brow + wave * 32 + 2 * (lane >> 3) + rho) * (int64_t)KDIM + sig * 8;
  const _Float16* const bsrcB =
      BH + (bcol + wave * 32 + 2 * (lane >> 3) + rho) * (int64_t)KDIM + sig * 8;

  // Fragment-read constants
  const int pX  = ((fr & 1) * 4 + fq) ^ ((fr >> 1) & 7);  // phys slot (lane-constant)
  const int frh = fr >> 1;
  const int jA0 = wr >> 1;
  const int jB0 = wc >> 1;

  // Stage one k-half (16KB): 2 gload_lds per thread (1KB each, 8 lines apiece)
#define STAGE_A(T, D, KH)                                                  \
  do {                                                                     \
    GLOAD_LDS16(asrcA + (T) * 64 + (KH) * 32,                              \
                &lA[D][KH][(wave * 16 + 0) * 64]);                         \
    GLOAD_LDS16(asrcA + (int64_t)16 * KDIM + (T) * 64 + (KH) * 32,         \
                &lA[D][KH][(wave * 16 + 8) * 64]);                         \
  } while (0)

#define STAGE_B(T, D, KH)                                                  \
  do {                                                                     \
    GLOAD_LDS16(bsrcB + (T) * 64 + (KH) * 32,                              \
                &lB[D][KH][(wave * 16 + 0) * 64]);                         \
    GLOAD_LDS16(bsrcB + (int64_t)16 * KDIM + (T) * 64 + (KH) * 32,         \
                &lB[D][KH][(wave * 16 + 8) * 64]);                         \
  } while (0)

#define DS_A(D, KS, G)                                                     \
  _Pragma("unroll") for (int i_ = 0; i_ < 4; ++i_)                         \
      af[i_] = *(const half8*)&lA[D][KS]                                   \
          [(jA0 + ((G) * 4 + i_) * 8 + frh) * 64 + pX * 8];

#define DS_B(D, KS)                                                        \
  _Pragma("unroll") for (int fn_ = 0; fn_ < 4; ++fn_)                      \
      bfr[fn_] = *(const half8*)&lB[D][KS]                                 \
          [(jB0 + fn_ * 8 + frh) * 64 + pX * 8];

#define MFMA16(G)                                                          \
  __builtin_amdgcn_s_setprio(1);                                           \
  _Pragma("unroll") for (int fm_ = 0; fm_ < 4; ++fm_)                      \
  _Pragma("unroll") for (int fn_ = 0; fn_ < 4; ++fn_)                      \
      acc[(G) * 4 + fm_][fn_] = __builtin_amdgcn_mfma_f32_16x16x32_f16(    \
          af[fm_], bfr[fn_], acc[(G) * 4 + fm_][fn_], 0, 0, 0);            \
  __builtin_amdgcn_s_setprio(0);

#define SB()    __builtin_amdgcn_sched_barrier(0)
#define BAR()   __builtin_amdgcn_s_barrier()
#define LGKM0() asm volatile("s_waitcnt lgkmcnt(0)" ::: "memory")
#define VMC(n)  asm volatile("s_waitcnt vmcnt(" #n ")" ::: "memory")

  // Steady-state window (tile T in buf BC; BN_ = buf of T+1 = BC^1).
  // Stage ledger (audited): p1: A-kh1(T+1)->lA[BN_][1]  (region dead since prev p4)
  //                         p2: B-kh0(T+2)->lB[BC][0]   (dead after this window's p1)
  //                         p3: A-kh0(T+2)->lA[BC][0]   (dead after p2)
  //                         p4: B-kh1(T+2)->lB[BC][1]   (dead after p3); ckpt vmcnt(6)
#define WIN(T, BC, BN_)                                                    \
  {                                                                        \
    half8 af[4], bfr[4];                                                   \
    /* p1 */                                                               \
    DS_B(BC, 0); DS_A(BC, 0, 0);                                           \
    STAGE_A((T) + 1, BN_, 1);                                              \
    SB(); BAR(); LGKM0(); SB();                                            \
    MFMA16(0);                                                             \
    SB(); BAR(); SB();                                                     \
    /* p2 */                                                               \
    DS_A(BC, 0, 1);                                                        \
    STAGE_B((T) + 2, BC, 0);                                               \
    SB(); BAR(); LGKM0(); SB();                                            \
    MFMA16(1);                                                             \
    SB(); BAR(); SB();                                                     \
    /* p3 */                                                               \
    DS_B(BC, 1); DS_A(BC, 1, 0);                                           \
    STAGE_A((T) + 2, BC, 0);                                               \
    SB(); BAR(); LGKM0(); SB();                                            \
    MFMA16(0);                                                             \
    SB(); BAR(); SB();                                                     \
    /* p4 */                                                               \
    DS_A(BC, 1, 1);                                                        \
    STAGE_B((T) + 2, BC, 1);                                               \
    SB(); BAR(); LGKM0(); SB();                                            \
    MFMA16(1);                                                             \
    SB(); VMC(6); BAR(); SB();                                             \
  }

  // ---- prologue: tile0 all 4 halves + tile1 {B-kh0, A-kh0, B-kh1} ----
  STAGE_B(0, 0, 0); STAGE_A(0, 0, 0); STAGE_B(0, 0, 1); STAGE_A(0, 0, 1);
  STAGE_B(1, 1, 0); STAGE_A(1, 1, 0); STAGE_B(1, 1, 1);
  SB(); VMC(6); BAR(); SB();   // tile0's 8 loads retired; tile1's 6 stay in flight

  for (int t = 0; t < 62; t += 2) {
    WIN(t, 0, 1);
    WIN(t + 1, 1, 0);
  }

  // ---- window 62 (buf 0): only p1 stage (A-kh1(63)); ckpt drains all ----
  {
    half8 af[4], bfr[4];
    DS_B(0, 0); DS_A(0, 0, 0);
    STAGE_A(63, 1, 1);
    SB(); BAR(); LGKM0(); SB();
    MFMA16(0);
    SB(); BAR(); SB();
    DS_A(0, 0, 1);
    SB(); BAR(); LGKM0(); SB();
    MFMA16(1);
    SB(); BAR(); SB();
    DS_B(0, 1); DS_A(0, 1, 0);
    SB(); BAR(); LGKM0(); SB();
    MFMA16(0);
    SB(); BAR(); SB();
    DS_A(0, 1, 1);
    SB(); BAR(); LGKM0(); SB();
    MFMA16(1);
    SB(); VMC(0); BAR(); SB();
  }
  // ---- window 63 (buf 1): nobody writes; no barriers needed ----
  {
    half8 af[4], bfr[4];
    DS_B(1, 0); DS_A(1, 0, 0);
    LGKM0(); SB();
    MFMA16(0);
    DS_A(1, 0, 1);
    LGKM0(); SB();
    MFMA16(1);
    DS_B(1, 1); DS_A(1, 1, 0);
    LGKM0(); SB();
    MFMA16(0);
    DS_A(1, 1, 1);
    LGKM0(); SB();
    MFMA16(1);
  }

  // ---- epilogue: C/D map col=lane&15, row=(lane>>4)*4+reg; fp32 out ----
#pragma unroll
  for (int fm = 0; fm < 8; ++fm)
#pragma unroll
    for (int fn = 0; fn < 4; ++fn)
#pragma unroll
      for (int r = 0; r < 4; ++r) {
        const int64_t row = brow + wr + fm * 16 + fq * 4 + r;
        const int     col = bcol + wc + fn * 16 + fr;
        OUT[row * NDIM + col] = acc[fm][fn][r];
      }
}

// ---------------- fallback (fp32-input, no workspace; proven r3 structure) ----------------
__global__ __launch_bounds__(512, 2)
void l4b_fb(const float* __restrict__ X, const int* __restrict__ PW,
            const float* __restrict__ SC, float* __restrict__ OUT)
{
  __shared__ alignas(16) _Float16 fla[2][256 * 64];
  __shared__ alignas(16) _Float16 flb[2][256 * 64];

  const int tid  = threadIdx.x;
  const int lane = tid & 63;
  const int wave = tid >> 6;

  const int cpx = (int)gridDim.x >> 3;
  const int wg  = ((int)blockIdx.x & 7) * cpx + ((int)blockIdx.x >> 3);
  const int by  = wg / 43;
  const int bx  = wg - by * 43;
  const int64_t brow = (int64_t)by * 256;
  const int     bcol = bx * 256;

  const int wr = (wave >> 2) * 128;
  const int wc = (wave & 3) * 64;
  const int fr = lane & 15;
  const int fq = lane >> 4;

  floatx4 acc[8][4];
#pragma unroll
  for (int i = 0; i < 8; ++i)
#pragma unroll
    for (int j = 0; j < 4; ++j) acc[i][j] = (floatx4)(0.0f);

  const int ar = tid >> 1;
  const int ah = tid & 1;
  const float* const aptr = X + (brow + ar) * (int64_t)KDIM + ah * 32;
  const int bc  = tid & 255;
  const int bkq = tid >> 8;
  const int*   const pwcol = PW + bcol + bc;
  const float* const sccol = SC + bcol + bc;

  floatx4 ra[8];
  int     rwf[4];
  float   rsc;

#define F_LOAD_A(t)                                                        \
  do {                                                                     \
    const float* ap = aptr + (t) * 64;                                     \
    _Pragma("unroll") for (int i_ = 0; i_ < 8; ++i_)                       \
        ra[i_] = *(const floatx4*)(ap + i_ * 4);                           \
  } while (0)

#define F_LOAD_B(t)                                                        \
  do {                                                                     \
    const int* pp = pwcol + ((t) * 8 + bkq) * NDIM;                        \
    _Pragma("unroll") for (int j_ = 0; j_ < 4; ++j_)                       \
        rwf[j_] = pp[j_ * 2 * NDIM];                                       \
    rsc = sccol[(int64_t)((t) >> 1) * NDIM];                               \
  } while (0)

#define F_WRITE_A(dst)                                                     \
  do {                                                                     \
    _Pragma("unroll") for (int i2 = 0; i2 < 4; ++i2) {                     \
      uint4v u;                                                            \
      u[0] = pkrtz(ra[2 * i2][0], ra[2 * i2][1]);                          \
      u[1] = pkrtz(ra[2 * i2][2], ra[2 * i2][3]);                          \
      u[2] = pkrtz(ra[2 * i2 + 1][0], ra[2 * i2 + 1][1]);                  \
      u[3] = pkrtz(ra[2 * i2 + 1][2], ra[2 * i2 + 1][3]);                  \
      const int s_ = ah * 4 + i2;                                          \
      *(half8*)&(dst)[ar * 64 + ((s_ ^ (ar & 7)) * 8)] =                   \
          __builtin_bit_cast(half8, u);                                    \
    }                                                                      \
  } while (0)

#define F_WRITE_B(dst)                                                     \
  do {                                                                     \
    const _Float16 ssf = (_Float16)(rsc * (1.0f / 7.5f));                  \
    half2v sv; sv[0] = ssf; sv[1] = ssf;                                   \
    _Pragma("unroll") for (int j_ = 0; j_ < 4; ++j_) {                     \
      half8 v = dq8((uint32_t)rwf[j_], sv);                                \
      const int kp = bkq + 2 * j_;                                         \
      *(half8*)&(dst)[bc * 64 + ((kp ^ (bc & 7)) * 8)] = v;                \
    }                                                                      \
  } while (0)

#define F_MFMA16(fm0)                                                      \
  __builtin_amdgcn_s_barrier();                                            \
  asm volatile("s_waitcnt lgkmcnt(0)" ::: "memory");                       \
  __builtin_amdgcn_sched_barrier(0);                                       \
  __builtin_amdgcn_s_setprio(1);                                           \
  _Pragma("unroll") for (int fm_ = 0; fm_ < 4; ++fm_)                      \
  _Pragma("unroll") for (int fn_ = 0; fn_ < 4; ++fn_)                      \
      acc[(fm0) + fm_][fn_] = __builtin_amdgcn_mfma_f32_16x16x32_f16(      \
          af[fm_], bfr[fn_], acc[(fm0) + fm_][fn_], 0, 0, 0);              \
  __builtin_amdgcn_s_setprio(0);                                           \
  __builtin_amdgcn_sched_barrier(0);                                       \
  __builtin_amdgcn_s_barrier();                                            \
  __builtin_amdgcn_sched_barrier(0);

  F_LOAD_A(0); F_LOAD_B(0);
  F_WRITE_A(fla[0]); F_WRITE_B(flb[0]);
  F_LOAD_A(1); F_LOAD_B(1);
  asm volatile("s_waitcnt lgkmcnt(0)" ::: "memory");
  __builtin_amdgcn_s_barrier();
  __builtin_amdgcn_sched_barrier(0);

  for (int kt = 0; kt < NKT; ++kt) {
    const int buf = kt & 1;
    const _Float16* lap = fla[buf];
    const _Float16* lbp = flb[buf];
    _Float16* const lan = fla[buf ^ 1];
    _Float16* const lbn = flb[buf ^ 1];
    const bool haveW = (kt + 1 < NKT);
    const bool haveL = (kt + 2 < NKT);

    half8 bfr[4], af[4];

#pragma unroll
    for (int fn_ = 0; fn_ < 4; ++fn_) {
      const int n_ = wc + fn_ * 16 + fr;
      bfr[fn_] = *(const half8*)&flb[buf][n_ * 64 + ((fq ^ (n_ & 7)) * 8)];
    }
#pragma unroll
    for (int fm_ = 0; fm_ < 4; ++fm_) {
      const int m_ = wr + fm_ * 16 + fr;
      af[fm_] = *(const half8*)&lap[m_ * 64 + ((fq ^ (m_ & 7)) * 8)];
    }
    if (haveW) F_WRITE_A(lan);
    F_MFMA16(0);

#pragma unroll
    for (int fm_ = 0; fm_ < 4; ++fm_) {
      const int m_ = wr + (4 + fm_) * 16 + fr;
      af[fm_] = *(const half8*)&lap[m_ * 64 + ((fq ^ (m_ & 7)) * 8)];
    }
    if (haveL) F_LOAD_A(kt + 2);
    F_MFMA16(4);

#pragma unroll
    for (int fn_ = 0; fn_ < 4; ++fn_) {
      const int n_ = wc + fn_ * 16 + fr;
      bfr[fn_] = *(const half8*)&lbp[n_ * 64 + (((4 + fq) ^ (n_ & 7)) * 8)];
    }
#pragma unroll
    for (int fm_ = 0; fm_ < 4; ++fm_) {
      const int m_ = wr + fm_ * 16 + fr;
      af[fm_] = *(const half8*)&lap[m_ * 64 + (((4 + fq) ^ (m_ & 7)) * 8)];
    }
    if (haveW) F_WRITE_B(lbn);
    F_MFMA16(0);

#pragma unroll
    for (int fm_ = 0; fm_ < 4; ++fm_) {
      const int m_ = wr + (4 + fm_) * 16 + fr;
      af[fm_] = *(const half8*)&lap[m_ * 64 + (((4 + fq) ^ (m_ & 7)) * 8)];
    }
    if (haveL) F_LOAD_B(kt + 2);
    F_MFMA16(4);
  }

#pragma unroll
  for (int fm = 0; fm < 8; ++fm)
#pragma unroll
    for (int fn = 0; fn < 4; ++fn)
#pragma unroll
      for (int r = 0; r < 4; ++r) {
        const int64_t row = brow + wr + fm * 16 + fq * 4 + r;
        const int     col = bcol + wc + fn * 16 + fr;
        OUT[row * NDIM + col] = acc[fm][fn][r];
      }
}

extern "C" void kernel_launch(void* const* d_in, const int* in_sizes, int n_in,
                              void* d_out, int out_size, void* d_ws, size_t ws_size,
                              hipStream_t stream) {
  const float* X   = (const float*)d_in[0];
  const int*   PW  = (const int*)d_in[1];
  const float* SC  = (const float*)d_in[2];
  float*       OUT = (float*)d_out;

  const int    M     = in_sizes[0] / KDIM;                 // 8192
  const size_t needH = (size_t)in_sizes[0] * 2;            // 67.1 MB fp16 X
  const size_t needB = (size_t)KDIM * NDIM * 2;            // 90.2 MB fp16 B
  const int    grid  = (M / 256) * (NDIM / 256);           // 1376

  if (ws_size >= needH + needB && (M % 256) == 0) {
    _Float16* XH = (_Float16*)d_ws;
    _Float16* BH = (_Float16*)((char*)d_ws + needH);
    const int n8 = in_sizes[0] / 8;
    l4b_prep<<<(n8 + 255) / 256, 256, 0, stream>>>(X, XH, n8);
    l4b_prepB<<<(KDIM / 64) * (NDIM / 64), 256, 0, stream>>>(PW, SC, BH);
    l4b_g7<<<grid, 512, 0, stream>>>(XH, BH, OUT);
  } else {
    l4b_fb<<<grid, 512, 0, stream>>>(X, PW, SC, OUT);
  }
}